// Round 2
// baseline (486.382 us; speedup 1.0000x reference)
//
#include <hip/hip_runtime.h>

typedef __attribute__((ext_vector_type(8))) __bf16 bf16x8;
typedef __attribute__((ext_vector_type(4))) float f32x4;
typedef __attribute__((ext_vector_type(8))) unsigned short u16x8;
typedef __attribute__((ext_vector_type(4))) unsigned short u16x4;

#define N_NODES 4000
#define LD 4096
#define D_EMB 10
#define NT 64  // K-tiles of 64 over zero-padded K=4096

__device__ __forceinline__ unsigned short f2bf(float f) {
  union { float f; unsigned int u; } v; v.f = f;
  unsigned int r = v.u + 0x7fffu + ((v.u >> 16) & 1u);
  return (unsigned short)(r >> 16);
}
__device__ __forceinline__ float bf2f(unsigned short s) {
  union { unsigned int u; float f; } v; v.u = ((unsigned int)s) << 16;
  return v.f;
}

#define AS1 __attribute__((address_space(1)))
#define AS3 __attribute__((address_space(3)))
__device__ __forceinline__ void gll16(const void* g, void* l) {
  __builtin_amdgcn_global_load_lds((const AS1 void*)g, (AS3 void*)l, 16, 0, 0);
}

// ---------- x [B,M,C] fp32 -> Xc [bc=b*64+c][m] bf16 (row stride 4096) ----------
__global__ __launch_bounds__(256) void transpose_x_kernel(const float* __restrict__ x,
                                                          unsigned short* __restrict__ Xc) {
  __shared__ float tl[64 * 65];
  const int t = threadIdx.x;
  const int m0 = blockIdx.x * 64;
  const int b = blockIdx.y;
#pragma unroll
  for (int rep = 0; rep < 16; ++rep) {
    int idx = rep * 256 + t;
    int ml = idx >> 6, c = idx & 63;
    int m = m0 + ml;
    tl[ml * 65 + c] = (m < N_NODES) ? x[(b * N_NODES + m) * 64 + c] : 0.f;
  }
  __syncthreads();
  const int c_out = t >> 2, q = t & 3;
  u16x8 v0, v1;
#pragma unroll
  for (int j = 0; j < 8; ++j) v0[j] = f2bf(tl[(q * 16 + j) * 65 + c_out]);
#pragma unroll
  for (int j = 0; j < 8; ++j) v1[j] = f2bf(tl[(q * 16 + 8 + j) * 65 + c_out]);
  unsigned short* dst = Xc + (size_t)(b * 64 + c_out) * LD + m0 + q * 16;
  *(u16x8*)dst = v0;
  *(u16x8*)(dst + 8) = v1;
}

// ---------- A = softmax(relu(emb @ emb^T)) rows, bf16; rows/cols 4000..4095 zeroed ----------
__global__ __launch_bounds__(256) void build_adj_kernel(const float* __restrict__ emb,
                                                        unsigned short* __restrict__ A) {
  __shared__ float e_lds[N_NODES];
  __shared__ float embn[16];
  __shared__ float red[16];
  const int n = blockIdx.x, t = threadIdx.x;
  if (n >= N_NODES) {
    for (int m = t; m < LD; m += 256) A[(size_t)n * LD + m] = 0;
    return;
  }
  if (t < D_EMB) embn[t] = emb[n * D_EMB + t];
  __syncthreads();
  float lsum = 0.f;
  for (int m = t; m < N_NODES; m += 256) {
    float dot = 0.f;
#pragma unroll
    for (int d = 0; d < D_EMB; ++d) dot += embn[d] * emb[m * D_EMB + d];
    float e = __expf(fmaxf(dot, 0.f));
    e_lds[m] = e;
    lsum += e;
  }
#pragma unroll
  for (int off = 32; off > 0; off >>= 1) lsum += __shfl_down(lsum, off, 64);
  const int lane = t & 63, wave = t >> 6;
  if (lane == 0) red[wave] = lsum;
  __syncthreads();
  if (t == 0) red[8] = 1.f / (red[0] + red[1] + red[2] + red[3]);
  __syncthreads();
  const float inv = red[8];
  for (int m = t; m < LD; m += 256) {
    float v = (m < N_NODES) ? e_lds[m] * inv : 0.f;
    A[(size_t)n * LD + m] = f2bf(v);
  }
}

// ---------- wp [10][3][64 i][64 o] fp32 -> wpT [10][o*192 + k*64 + i] bf16 ----------
__global__ __launch_bounds__(256) void wpt_kernel(const float* __restrict__ wp,
                                                  unsigned short* __restrict__ wpT) {
  __shared__ float tl[64 * 65];
  const int dk = blockIdx.x;  // 30 blocks: d*3+k
  const int d = dk / 3, k = dk % 3;
  const float* src = wp + (size_t)dk * 4096;
  const int t = threadIdx.x;
#pragma unroll
  for (int rep = 0; rep < 16; ++rep) {
    int idx = rep * 256 + t;
    tl[(idx >> 6) * 65 + (idx & 63)] = src[idx];
  }
  __syncthreads();
#pragma unroll
  for (int rep = 0; rep < 16; ++rep) {
    int idx = rep * 256 + t;
    int o = idx >> 6, i = idx & 63;
    wpT[(size_t)d * 12288 + o * 192 + k * 64 + i] = f2bf(tl[i * 65 + o]);
  }
}

// ---------- W_all[n][j] = sum_d emb[n,d] * wpT[d][j]  (j = o*192+ki), bf16 ----------
__global__ __launch_bounds__(256) void wgen_kernel(const float* __restrict__ emb,
                                                   const unsigned short* __restrict__ wpT,
                                                   unsigned short* __restrict__ W_all) {
  __shared__ float el[50 * D_EMB];
  const int t = threadIdx.x;
  const int j = blockIdx.x * 256 + t;
  const int n0 = blockIdx.y * 50;
  for (int idx = t; idx < 50 * D_EMB; idx += 256) el[idx] = emb[n0 * D_EMB + idx];
  __syncthreads();
  float w[D_EMB];
#pragma unroll
  for (int d = 0; d < D_EMB; ++d) w[d] = bf2f(wpT[(size_t)d * 12288 + j]);
  for (int n = 0; n < 50; ++n) {
    float a = 0.f;
#pragma unroll
    for (int d = 0; d < D_EMB; ++d) a += el[n * D_EMB + d] * w[d];
    W_all[(size_t)(n0 + n) * 12288 + j] = f2bf(a);
  }
}

// ---------- C = A @ B^T, 256x256 tile, BK=64, ks-split 8-phase (T2+T3+T4+T5) ----------
// 8 waves (2M x 4N), per-wave 128x64 output. Per K-tile: 4 phases = (mh, ks) quadrants,
// each {READ 4A(+4B) frags; stage 1 ks-slice (2 gll16); BAR; lgkm0; setprio1; 16 MFMA;
// setprio0; [vmcnt]; BAR}. Balanced reads {8,4,8,4} (was {12,4,8,0}).
// LDS 128 KiB: per buffer A[2ks][256][32k] + B[2ks][256][32k], 64-B rows.
// Swizzle: 16B slot = quad ^ ((row>>1)&3)  (2-way worst on b128 = free, m136);
// inverse applied on pre-swizzled GLOBAL source (gll16 writes linearly).
// Staging per tile t: P1: A-ks1(t+1)->Q, P2: B-ks0(t+2)->P, P3: A-ks0(t+2)->P,
// P4: B-ks1(t+1)->Q. Region-safety: each P-region staged only after its last in-tile
// read drained (lgkm0 + barrier). Ledger (2 loads/unit, in-order vmcnt retirement):
//   P2 tail vmcnt(4): covers B-ks1(t)/A-ks1(t) for P3 reads.
//   P4 tail vmcnt(10): covers A-ks0(t+1)/B-ks0(t+1) for P1(t+1) reads.
template <bool WRITE_T>
__global__ __launch_bounds__(512, 2) void gemm256_kernel(const unsigned short* __restrict__ Amat,
                                                         const unsigned short* __restrict__ Bmat,
                                                         unsigned short* __restrict__ Cn,
                                                         unsigned short* __restrict__ Ct) {
  __shared__ __align__(128) char smem[131072];
  const int tid = threadIdx.x;
  const int wave = tid >> 6, lane = tid & 63;
  const int wr = wave >> 2, wc = wave & 3;
  const int bm = blockIdx.y * 256, bn = blockIdx.x * 256;
  const int l15 = lane & 15, quad = lane >> 4;
  const int slotb = ((quad ^ ((l15 >> 1) & 3)) << 4);  // swizzled 16B slot within 64-B row

  // read bases: + P*32768 + ks*16384 (+ mh*4096 + m*1024 for A, + n*1024 for B)
  const char* Ard = smem + (wr * 128 + l15) * 64 + slotb;
  const char* Brd = smem + 65536 + (wc * 64 + l15) * 64 + slotb;

  // staging: per-thread pre-swizzled global source (inverse of read swizzle)
  const int u2 = tid >> 2;                                // row_local 0..127
  const int kseg = (tid & 3) ^ ((u2 >> 1) & 3);           // k-seg stored at this slot
  const unsigned short* gA = Amat + (size_t)(bm + u2) * LD + kseg * 8;
  const unsigned short* gB = Bmat + (size_t)(bn + u2) * LD + kseg * 8;
  // LDS dests (wave-uniform; HW adds lane*16): + P*32768 + ks*16384 (+8192 for rows 128..255)
  char* dA = smem + wave * 1024;
  char* dB = smem + 65536 + wave * 1024;

#define STAGE_A(P, KS, KT) do { \
    gll16(gA + (KT) * 64 + (KS) * 32,                      dA + (P) * 32768 + (KS) * 16384); \
    gll16(gA + (size_t)128 * LD + (KT) * 64 + (KS) * 32,   dA + (P) * 32768 + (KS) * 16384 + 8192); \
  } while (0)
#define STAGE_B(P, KS, KT) do { \
    gll16(gB + (KT) * 64 + (KS) * 32,                      dB + (P) * 32768 + (KS) * 16384); \
    gll16(gB + (size_t)128 * LD + (KT) * 64 + (KS) * 32,   dB + (P) * 32768 + (KS) * 16384 + 8192); \
  } while (0)
#define BAR __builtin_amdgcn_s_barrier()
#define LGKM0 asm volatile("s_waitcnt lgkmcnt(0)" ::: "memory")
#define VM4  asm volatile("s_waitcnt vmcnt(4)" ::: "memory")
#define VM8  asm volatile("s_waitcnt vmcnt(8)" ::: "memory")
#define VM10 asm volatile("s_waitcnt vmcnt(10)" ::: "memory")

  f32x4 acc[8][4] = {};
  bf16x8 af[4], bf[4];

#define READ_AF(P, KS, MH) do { _Pragma("unroll") for (int m = 0; m < 4; ++m) \
    af[m] = *(const bf16x8*)(Ard + (P) * 32768 + (KS) * 16384 + (MH) * 4096 + m * 1024); } while (0)
#define READ_BF(P, KS) do { _Pragma("unroll") for (int n = 0; n < 4; ++n) \
    bf[n] = *(const bf16x8*)(Brd + (P) * 32768 + (KS) * 16384 + n * 1024); } while (0)
#define MFMA4x4(MH) do { _Pragma("unroll") for (int m = 0; m < 4; ++m) \
    _Pragma("unroll") for (int n = 0; n < 4; ++n) \
      acc[(MH) * 4 + m][n] = __builtin_amdgcn_mfma_f32_16x16x32_bf16(af[m], bf[n], acc[(MH) * 4 + m][n], 0, 0, 0); } while (0)

  // prologue: issue order primes the steady-state ledger
  STAGE_B(0, 0, 0);   // B-ks0(0)
  STAGE_A(0, 0, 0);   // A-ks0(0)
  STAGE_A(0, 1, 0);   // A-ks1(0)
  STAGE_B(1, 0, 1);   // B-ks0(1)
  STAGE_A(1, 0, 1);   // A-ks0(1)
  STAGE_B(0, 1, 0);   // B-ks1(0)
  VM8;                // A-ks0(0)+B-ks0(0) complete (4 newer units allowed)
  BAR;

#define TILE(T, P) do { \
    /* P1: (mh0, ks0) */ \
    READ_AF(P, 0, 0); READ_BF(P, 0); \
    STAGE_A((P) ^ 1, 1, ((T) + 1 < NT ? (T) + 1 : 0)); \
    BAR; LGKM0; \
    __builtin_amdgcn_s_setprio(1); MFMA4x4(0); __builtin_amdgcn_s_setprio(0); \
    BAR; \
    /* P2: (mh1, ks0) */ \
    READ_AF(P, 0, 1); \
    STAGE_B(P, 0, ((T) + 2 < NT ? (T) + 2 : 0)); \
    BAR; LGKM0; \
    __builtin_amdgcn_s_setprio(1); MFMA4x4(1); __builtin_amdgcn_s_setprio(0); \
    VM4; BAR; \
    /* P3: (mh0, ks1) */ \
    READ_AF(P, 1, 0); READ_BF(P, 1); \
    STAGE_A(P, 0, ((T) + 2 < NT ? (T) + 2 : 0)); \
    BAR; LGKM0; \
    __builtin_amdgcn_s_setprio(1); MFMA4x4(0); __builtin_amdgcn_s_setprio(0); \
    BAR; \
    /* P4: (mh1, ks1) */ \
    READ_AF(P, 1, 1); \
    STAGE_B((P) ^ 1, 1, ((T) + 1 < NT ? (T) + 1 : 0)); \
    BAR; LGKM0; \
    __builtin_amdgcn_s_setprio(1); MFMA4x4(1); __builtin_amdgcn_s_setprio(0); \
    VM10; BAR; \
  } while (0)

#pragma unroll 1
  for (int t = 0; t < NT; t += 2) {
    TILE(t, 0);
    TILE(t + 1, 1);
  }

  // direct C write (registers only)
#pragma unroll
  for (int mt = 0; mt < 8; ++mt)
#pragma unroll
    for (int nt = 0; nt < 4; ++nt) {
      const int row0 = bm + wr * 128 + mt * 16 + quad * 4;
      const int col = bn + wc * 64 + nt * 16 + l15;
#pragma unroll
      for (int r = 0; r < 4; ++r)
        Cn[(size_t)(row0 + r) * LD + col] = f2bf(acc[mt][nt][r]);
    }

  if (WRITE_T) {
    unsigned short* tr = (unsigned short*)smem;  // [128 cols][264] per chunk
    asm volatile("s_waitcnt vmcnt(0)" ::: "memory");  // drain dead prefetches before smem reuse
    __syncthreads();
#pragma unroll
    for (int ch = 0; ch < 2; ++ch) {
      if ((wc >> 1) == ch) {
#pragma unroll
        for (int mt = 0; mt < 8; ++mt)
#pragma unroll
          for (int nt = 0; nt < 4; ++nt) {
            const int coll = (wc & 1) * 64 + nt * 16 + l15;
            const int row0 = wr * 128 + mt * 16 + quad * 4;
#pragma unroll
            for (int r = 0; r < 4; ++r)
              tr[coll * 264 + row0 + r] = f2bf(acc[mt][nt][r]);
          }
      }
      __syncthreads();
      {
        const int coll = tid >> 2, seg = tid & 3;
        const unsigned short* src = tr + coll * 264 + seg * 64;
        unsigned short* dst = Ct + (size_t)(bn + ch * 128 + coll) * LD + bm + seg * 64;
#pragma unroll
        for (int j = 0; j < 8; ++j)
          *(u16x8*)(dst + j * 8) = *(const u16x8*)(src + j * 8);
      }
      __syncthreads();
    }
  } else {
    asm volatile("s_waitcnt vmcnt(0)" ::: "memory");  // drain dead prefetches before endpgm
  }
#undef TILE
#undef MFMA4x4
#undef READ_BF
#undef READ_AF
#undef VM10
#undef VM8
#undef VM4
#undef LGKM0
#undef BAR
#undef STAGE_B
#undef STAGE_A
}

// ---------- fused per-node epilogue via MFMA; W streamed from precomputed W_all ----------
#define EST 200  // LDS row stride (elements): 400 B, 16-B aligned
__global__ __launch_bounds__(256) void epilogue_kernel(const float* __restrict__ x,
                                                       const float* __restrict__ emb,
                                                       const unsigned short* __restrict__ W_all,
                                                       const float* __restrict__ bp,
                                                       const unsigned short* __restrict__ Y1,
                                                       const unsigned short* __restrict__ Y2,
                                                       float* __restrict__ out) {
  __shared__ unsigned short Wt[64 * EST];  // [o][ki]
  __shared__ unsigned short xg[64 * EST];  // [b][ki]
  __shared__ float embn[16];
  const int n = blockIdx.x, t = threadIdx.x;
  if (t < D_EMB) embn[t] = emb[n * D_EMB + t];

  {
    const int o = t >> 2, sub = t & 3;
    const unsigned short* srcW = W_all + (size_t)n * 12288 + o * 192 + sub * 48;
    unsigned short* dstW = Wt + o * EST + sub * 48;
#pragma unroll
    for (int c = 0; c < 6; ++c)
      *(u16x8*)(dstW + c * 8) = *(const u16x8*)(srcW + c * 8);
  }
  for (int idx = t; idx < 1024; idx += 256) {
    int b = idx >> 4, c4 = (idx & 15) * 4;
    f32x4 v = *(const f32x4*)(x + (size_t)(b * N_NODES + n) * 64 + c4);
    u16x4 s;
#pragma unroll
    for (int j = 0; j < 4; ++j) s[j] = f2bf(v[j]);
    *(u16x4*)(xg + b * EST + c4) = s;
  }
  for (int idx = t; idx < 512; idx += 256) {
    int b = idx >> 3, c8 = (idx & 7) * 8;
    *(u16x8*)(xg + b * EST + 64 + c8) = *(const u16x8*)(Y1 + (size_t)n * LD + b * 64 + c8);
  }
  __syncthreads();
  for (int idx = t; idx < 512; idx += 256) {
    int b = idx >> 3, c8 = (idx & 7) * 8;
    u16x8 y2 = *(const u16x8*)(Y2 + (size_t)n * LD + b * 64 + c8);
    u16x8 r;
#pragma unroll
    for (int j = 0; j < 8; ++j)
      r[j] = f2bf(2.f * bf2f(y2[j]) - bf2f(xg[b * EST + c8 + j]));
    *(u16x8*)(xg + b * EST + 128 + c8) = r;
  }
  __syncthreads();

  const int wave = t >> 6, lane = t & 63, quad = lane >> 4;
  const unsigned short* Apx = xg + (wave * 16 + (lane & 15)) * EST + quad * 8;
  f32x4 acc[4] = {};
#pragma unroll
  for (int step = 0; step < 6; ++step) {
    int koff = step * 32;
    bf16x8 a = *(const bf16x8*)(Apx + koff);
#pragma unroll
    for (int nt = 0; nt < 4; ++nt) {
      bf16x8 bfr = *(const bf16x8*)(Wt + (nt * 16 + (lane & 15)) * EST + quad * 8 + koff);
      acc[nt] = __builtin_amdgcn_mfma_f32_16x16x32_bf16(a, bfr, acc[nt], 0, 0, 0);
    }
  }
  float bias[4];
#pragma unroll
  for (int nt = 0; nt < 4; ++nt) {
    float a = 0.f;
#pragma unroll
    for (int d = 0; d < D_EMB; ++d) a += embn[d] * bp[d * 64 + nt * 16 + (lane & 15)];
    bias[nt] = a;
  }
#pragma unroll
  for (int nt = 0; nt < 4; ++nt)
#pragma unroll
    for (int rr = 0; rr < 4; ++rr) {
      int b_row = wave * 16 + quad * 4 + rr;
      out[(size_t)(b_row * N_NODES + n) * 64 + nt * 16 + (lane & 15)] = acc[nt][rr] + bias[nt];
    }
}

extern "C" void kernel_launch(void* const* d_in, const int* in_sizes, int n_in,
                              void* d_out, int out_size, void* d_ws, size_t ws_size,
                              hipStream_t stream) {
  const float* x   = (const float*)d_in[0];
  const float* emb = (const float*)d_in[1];
  const float* wp  = (const float*)d_in[2];
  const float* bp  = (const float*)d_in[3];
  float* out = (float*)d_out;

  const size_t S = (size_t)LD * LD;
  unsigned short* Y1    = (unsigned short*)d_ws;      // slot 0 (live at epilogue)
  unsigned short* Y2    = Y1 + S;                     // slot 1 (live at epilogue)
  unsigned short* Xc    = Y1 + 2 * S;                 // slot 2
  unsigned short* Am    = Y1 + 3 * S;                 // slot 3
  unsigned short* Y1t   = Y1 + 4 * S;                 // slot 4
  unsigned short* wpT   = Xc;                         // 123 KB, written after GEMM2
  unsigned short* W_all = Xc + 256 * 1024;            // 98.3 MB, spans slots 2-4 tail

  transpose_x_kernel<<<dim3(64, 64), 256, 0, stream>>>(x, Xc);
  build_adj_kernel<<<LD, 256, 0, stream>>>(emb, Am);
  gemm256_kernel<true ><<<dim3(16, 16), 512, 0, stream>>>(Am, Xc, Y1, Y1t);
  gemm256_kernel<false><<<dim3(16, 16), 512, 0, stream>>>(Am, Y1t, Y2, nullptr);
  wpt_kernel<<<30, 256, 0, stream>>>(wp, wpT);
  wgen_kernel<<<dim3(48, 80), 256, 0, stream>>>(emb, wpT, W_all);
  epilogue_kernel<<<N_NODES, 256, 0, stream>>>(x, emb, W_all, bp, Y1, Y2, out);
}

// Round 3
// 480.402 us; speedup vs baseline: 1.0124x; 1.0124x over previous
//
#include <hip/hip_runtime.h>

typedef __attribute__((ext_vector_type(8))) __bf16 bf16x8;
typedef __attribute__((ext_vector_type(4))) float f32x4;
typedef __attribute__((ext_vector_type(8))) unsigned short u16x8;
typedef __attribute__((ext_vector_type(4))) unsigned short u16x4;

#define N_NODES 4000
#define LD 4096
#define D_EMB 10
#define NT 64  // K-tiles of 64 over zero-padded K=4096

__device__ __forceinline__ unsigned short f2bf(float f) {
  union { float f; unsigned int u; } v; v.f = f;
  unsigned int r = v.u + 0x7fffu + ((v.u >> 16) & 1u);
  return (unsigned short)(r >> 16);
}
__device__ __forceinline__ float bf2f(unsigned short s) {
  union { unsigned int u; float f; } v; v.u = ((unsigned int)s) << 16;
  return v.f;
}

#define AS1 __attribute__((address_space(1)))
#define AS3 __attribute__((address_space(3)))
__device__ __forceinline__ void gll16(const void* g, void* l) {
  __builtin_amdgcn_global_load_lds((const AS1 void*)g, (AS3 void*)l, 16, 0, 0);
}

// ---------- x [B,M,C] fp32 -> Xc [bc=b*64+c][m] bf16 (row stride 4096) ----------
__global__ __launch_bounds__(256) void transpose_x_kernel(const float* __restrict__ x,
                                                          unsigned short* __restrict__ Xc) {
  __shared__ float tl[64 * 65];
  const int t = threadIdx.x;
  const int m0 = blockIdx.x * 64;
  const int b = blockIdx.y;
#pragma unroll
  for (int rep = 0; rep < 16; ++rep) {
    int idx = rep * 256 + t;
    int ml = idx >> 6, c = idx & 63;
    int m = m0 + ml;
    tl[ml * 65 + c] = (m < N_NODES) ? x[(b * N_NODES + m) * 64 + c] : 0.f;
  }
  __syncthreads();
  const int c_out = t >> 2, q = t & 3;
  u16x8 v0, v1;
#pragma unroll
  for (int j = 0; j < 8; ++j) v0[j] = f2bf(tl[(q * 16 + j) * 65 + c_out]);
#pragma unroll
  for (int j = 0; j < 8; ++j) v1[j] = f2bf(tl[(q * 16 + 8 + j) * 65 + c_out]);
  unsigned short* dst = Xc + (size_t)(b * 64 + c_out) * LD + m0 + q * 16;
  *(u16x8*)dst = v0;
  *(u16x8*)(dst + 8) = v1;
}

// ---------- A = softmax(relu(emb @ emb^T)) rows, bf16; rows/cols 4000..4095 zeroed ----------
__global__ __launch_bounds__(256) void build_adj_kernel(const float* __restrict__ emb,
                                                        unsigned short* __restrict__ A) {
  __shared__ float e_lds[N_NODES];
  __shared__ float embn[16];
  __shared__ float red[16];
  const int n = blockIdx.x, t = threadIdx.x;
  if (n >= N_NODES) {
    for (int m = t; m < LD; m += 256) A[(size_t)n * LD + m] = 0;
    return;
  }
  if (t < D_EMB) embn[t] = emb[n * D_EMB + t];
  __syncthreads();
  float lsum = 0.f;
  for (int m = t; m < N_NODES; m += 256) {
    float dot = 0.f;
#pragma unroll
    for (int d = 0; d < D_EMB; ++d) dot += embn[d] * emb[m * D_EMB + d];
    float e = __expf(fmaxf(dot, 0.f));
    e_lds[m] = e;
    lsum += e;
  }
#pragma unroll
  for (int off = 32; off > 0; off >>= 1) lsum += __shfl_down(lsum, off, 64);
  const int lane = t & 63, wave = t >> 6;
  if (lane == 0) red[wave] = lsum;
  __syncthreads();
  if (t == 0) red[8] = 1.f / (red[0] + red[1] + red[2] + red[3]);
  __syncthreads();
  const float inv = red[8];
  for (int m = t; m < LD; m += 256) {
    float v = (m < N_NODES) ? e_lds[m] * inv : 0.f;
    A[(size_t)n * LD + m] = f2bf(v);
  }
}

// ---------- wp [10][3][64 i][64 o] fp32 -> wpT [10][o*192 + k*64 + i] bf16 ----------
__global__ __launch_bounds__(256) void wpt_kernel(const float* __restrict__ wp,
                                                  unsigned short* __restrict__ wpT) {
  __shared__ float tl[64 * 65];
  const int dk = blockIdx.x;  // 30 blocks: d*3+k
  const int d = dk / 3, k = dk % 3;
  const float* src = wp + (size_t)dk * 4096;
  const int t = threadIdx.x;
#pragma unroll
  for (int rep = 0; rep < 16; ++rep) {
    int idx = rep * 256 + t;
    tl[(idx >> 6) * 65 + (idx & 63)] = src[idx];
  }
  __syncthreads();
#pragma unroll
  for (int rep = 0; rep < 16; ++rep) {
    int idx = rep * 256 + t;
    int o = idx >> 6, i = idx & 63;
    wpT[(size_t)d * 12288 + o * 192 + k * 64 + i] = f2bf(tl[i * 65 + o]);
  }
}

// ---------- W_all[n][j] = sum_d emb[n,d] * wpT[d][j]  (j = o*192+ki), bf16 ----------
__global__ __launch_bounds__(256) void wgen_kernel(const float* __restrict__ emb,
                                                   const unsigned short* __restrict__ wpT,
                                                   unsigned short* __restrict__ W_all) {
  __shared__ float el[50 * D_EMB];
  const int t = threadIdx.x;
  const int j = blockIdx.x * 256 + t;
  const int n0 = blockIdx.y * 50;
  for (int idx = t; idx < 50 * D_EMB; idx += 256) el[idx] = emb[n0 * D_EMB + idx];
  __syncthreads();
  float w[D_EMB];
#pragma unroll
  for (int d = 0; d < D_EMB; ++d) w[d] = bf2f(wpT[(size_t)d * 12288 + j]);
  for (int n = 0; n < 50; ++n) {
    float a = 0.f;
#pragma unroll
    for (int d = 0; d < D_EMB; ++d) a += el[n * D_EMB + d] * w[d];
    W_all[(size_t)(n0 + n) * 12288 + j] = f2bf(a);
  }
}

// ---------- C = A @ B^T, 256x256 tile, BK=64, m201-quadrant 8-phase ----------
// 8 waves (2M x 4N), per-wave 128x64 output = 8x4 frags of 16x16x32 bf16.
// KEY vs R0/R2: four DISJOINT operand register sets a0,a1,b0,b1 (96 VGPR) so each
// phase's ds_reads never WAR against the previous phase's in-flight MFMA cluster
// (rewrite distance >= 2 phases). Consumption: P1:a0*b0 P2:a0*b1 P3:a1*b0 P4:a1*b1.
// LDS 128 KiB: A[2][256][64] + B[2][256][64] bf16, 128-B rows; XOR swizzle
// slot ^= (row&7) on reads, inverse pre-applied on the GLOBAL source (gll16 writes
// linearly). Half-tiles: A-H0 rows {0..63}u{128..191}, A-H1 rows {64..127}u{192..255},
// B-H0 rows wc*64+[0,32), B-H1 rows wc*64+[32,64).
// Staging: P1->A-H1(t+1) [other buf], P2->A-H0(t+2), P3->B-H0(t+2), P4->B-H1(t+2)
// [current buf, region dead after its consuming phase's closing barrier].
// ONE vmcnt(6) per tile at P4: force-drains all 4 half-tiles of t+1 (leads 3-6 phases).
template <bool WRITE_T>
__global__ __launch_bounds__(512, 2) void gemm256_kernel(const unsigned short* __restrict__ Amat,
                                                         const unsigned short* __restrict__ Bmat,
                                                         unsigned short* __restrict__ Cn,
                                                         unsigned short* __restrict__ Ct) {
  __shared__ __align__(128) char smem[131072];
  const int tid = threadIdx.x;
  const int wave = tid >> 6, lane = tid & 63;
  const int wr = wave >> 2, wc = wave & 3;
  const int bm = blockIdx.y * 256, bn = blockIdx.x * 256;
  const int l15 = lane & 15, quad = lane >> 4;
  const int swz = (lane & 7) << 4;           // row&7 == lane&7 for all frag reads
  const int k0 = (quad * 16) ^ swz;          // ks=0 swizzled col-byte
  const int k1 = (64 + quad * 16) ^ swz;     // ks=1

  const char* Ard = smem + (wr * 128 + l15) * 128;          // + P*32768 + mt*2048 + k0/k1
  const char* Brd = smem + 65536 + (wc * 64 + l15) * 128;   // + P*32768 + nt*2048 + k0/k1

  // staging: per-thread pre-swizzled global bases
  const int u = tid >> 3;
  const int xc = ((tid & 7) ^ (u & 7)) << 3;  // element offset, inverse of read swizzle
  const unsigned short* gA = Amat + (size_t)(bm + u) * LD + xc;
  const unsigned short* gB = Bmat + (size_t)(bn + (u >> 5) * 64 + (u & 31)) * LD + xc;
  // staging LDS dest (wave-uniform; HW adds lane*16)
  char* dA = smem + wave * 1024;
  char* dB = smem + 65536 + (wave >> 2) * 8192 + (wave & 3) * 1024;

#define STAGE_A(P, H, KT) do { \
    gll16(gA + (size_t)((H) * 64) * LD + (KT) * 64,       dA + (P) * 32768 + (H) * 8192); \
    gll16(gA + (size_t)((H) * 64 + 128) * LD + (KT) * 64, dA + (P) * 32768 + (H) * 8192 + 16384); \
  } while (0)
#define STAGE_B(P, H, KT) do { \
    gll16(gB + (size_t)((H) * 32) * LD + (KT) * 64,       dB + (P) * 32768 + (H) * 4096); \
    gll16(gB + (size_t)((H) * 32 + 128) * LD + (KT) * 64, dB + (P) * 32768 + (H) * 4096 + 16384); \
  } while (0)
#define BAR __builtin_amdgcn_s_barrier()
#define LGKM0 asm volatile("s_waitcnt lgkmcnt(0)" ::: "memory")
#define LGKM8 asm volatile("s_waitcnt lgkmcnt(8)" ::: "memory")
#define VM6  asm volatile("s_waitcnt vmcnt(6)" ::: "memory")

  f32x4 acc[8][4] = {};
  bf16x8 a0[4][2], a1[4][2], b0[2][2], b1[2][2];

#define READ_A(DST, MH, P) do { _Pragma("unroll") for (int m = 0; m < 4; ++m) { \
    DST[m][0] = *(const bf16x8*)(Ard + (P) * 32768 + ((MH) * 4 + m) * 2048 + k0); \
    DST[m][1] = *(const bf16x8*)(Ard + (P) * 32768 + ((MH) * 4 + m) * 2048 + k1); } } while (0)
#define READ_B(DST, NH, P) do { _Pragma("unroll") for (int n = 0; n < 2; ++n) { \
    DST[n][0] = *(const bf16x8*)(Brd + (P) * 32768 + ((NH) * 2 + n) * 2048 + k0); \
    DST[n][1] = *(const bf16x8*)(Brd + (P) * 32768 + ((NH) * 2 + n) * 2048 + k1); } } while (0)
#define MFMA_Q(AR, BR, MH, NH) do { _Pragma("unroll") for (int m = 0; m < 4; ++m) \
    _Pragma("unroll") for (int n = 0; n < 2; ++n) { \
      f32x4 c = acc[(MH) * 4 + m][(NH) * 2 + n]; \
      c = __builtin_amdgcn_mfma_f32_16x16x32_bf16(AR[m][0], BR[n][0], c, 0, 0, 0); \
      c = __builtin_amdgcn_mfma_f32_16x16x32_bf16(AR[m][1], BR[n][1], c, 0, 0, 0); \
      acc[(MH) * 4 + m][(NH) * 2 + n] = c; } } while (0)

  // prologue: FIFO order matches steady state; vmcnt(6) drains all of tile 0
  STAGE_A(0, 0, 0);   // A-H0(0)
  STAGE_B(0, 0, 0);   // B-H0(0)
  STAGE_B(0, 1, 0);   // B-H1(0)
  STAGE_A(0, 1, 0);   // A-H1(0)
  STAGE_A(1, 0, 1);   // A-H0(1)
  STAGE_B(1, 0, 1);   // B-H0(1)
  STAGE_B(1, 1, 1);   // B-H1(1)
  VM6;
  BAR;

#define TILE(T, P) do { \
    const int kt1 = ((T) + 1 < NT) ? (T) + 1 : 0; /* clamped: dead loads, live vmcnt count */ \
    const int kt2 = ((T) + 2 < NT) ? (T) + 2 : 0; \
    /* P1: a0*b0 (12 reads) */ \
    READ_A(a0, 0, P); READ_B(b0, 0, P); \
    STAGE_A((P) ^ 1, 1, kt1); \
    LGKM8; \
    BAR; LGKM0; \
    __builtin_amdgcn_s_setprio(1); MFMA_Q(a0, b0, 0, 0); __builtin_amdgcn_s_setprio(0); \
    BAR; \
    /* P2: a0*b1 (4 reads) */ \
    READ_B(b1, 1, P); \
    STAGE_A(P, 0, kt2); \
    BAR; LGKM0; \
    __builtin_amdgcn_s_setprio(1); MFMA_Q(a0, b1, 0, 1); __builtin_amdgcn_s_setprio(0); \
    BAR; \
    /* P3: a1*b0 (8 reads) */ \
    READ_A(a1, 1, P); \
    STAGE_B(P, 0, kt2); \
    BAR; LGKM0; \
    __builtin_amdgcn_s_setprio(1); MFMA_Q(a1, b0, 1, 0); __builtin_amdgcn_s_setprio(0); \
    BAR; \
    /* P4: a1*b1 (0 reads) */ \
    STAGE_B(P, 1, kt2); \
    VM6; \
    BAR; \
    __builtin_amdgcn_s_setprio(1); MFMA_Q(a1, b1, 1, 1); __builtin_amdgcn_s_setprio(0); \
    BAR; \
  } while (0)

#pragma unroll 1
  for (int t = 0; t < NT; t += 2) {
    TILE(t, 0);
    TILE(t + 1, 1);
  }

  // direct C write (registers only)
#pragma unroll
  for (int mt = 0; mt < 8; ++mt)
#pragma unroll
    for (int nt = 0; nt < 4; ++nt) {
      const int row0 = bm + wr * 128 + mt * 16 + quad * 4;
      const int col = bn + wc * 64 + nt * 16 + l15;
#pragma unroll
      for (int r = 0; r < 4; ++r)
        Cn[(size_t)(row0 + r) * LD + col] = f2bf(acc[mt][nt][r]);
    }

  if (WRITE_T) {
    unsigned short* tr = (unsigned short*)smem;  // [128 cols][264] per chunk
    asm volatile("s_waitcnt vmcnt(0)" ::: "memory");  // drain dead prefetches before smem reuse
    __syncthreads();
#pragma unroll
    for (int ch = 0; ch < 2; ++ch) {
      if ((wc >> 1) == ch) {
#pragma unroll
        for (int mt = 0; mt < 8; ++mt)
#pragma unroll
          for (int nt = 0; nt < 4; ++nt) {
            const int coll = (wc & 1) * 64 + nt * 16 + l15;
            const int row0 = wr * 128 + mt * 16 + quad * 4;
#pragma unroll
            for (int r = 0; r < 4; ++r)
              tr[coll * 264 + row0 + r] = f2bf(acc[mt][nt][r]);
          }
      }
      __syncthreads();
      {
        const int coll = tid >> 2, seg = tid & 3;
        const unsigned short* src = tr + coll * 264 + seg * 64;
        unsigned short* dst = Ct + (size_t)(bn + ch * 128 + coll) * LD + bm + seg * 64;
#pragma unroll
        for (int j = 0; j < 8; ++j)
          *(u16x8*)(dst + j * 8) = *(const u16x8*)(src + j * 8);
      }
      __syncthreads();
    }
  } else {
    asm volatile("s_waitcnt vmcnt(0)" ::: "memory");  // drain dead prefetches before endpgm
  }
#undef TILE
#undef MFMA_Q
#undef READ_B
#undef READ_A
#undef VM6
#undef LGKM8
#undef LGKM0
#undef BAR
#undef STAGE_B
#undef STAGE_A
}

// ---------- fused per-node epilogue via MFMA; W streamed from precomputed W_all ----------
#define EST 200  // LDS row stride (elements): 400 B, 16-B aligned
__global__ __launch_bounds__(256) void epilogue_kernel(const float* __restrict__ x,
                                                       const float* __restrict__ emb,
                                                       const unsigned short* __restrict__ W_all,
                                                       const float* __restrict__ bp,
                                                       const unsigned short* __restrict__ Y1,
                                                       const unsigned short* __restrict__ Y2,
                                                       float* __restrict__ out) {
  __shared__ unsigned short Wt[64 * EST];  // [o][ki]
  __shared__ unsigned short xg[64 * EST];  // [b][ki]
  __shared__ float embn[16];
  const int n = blockIdx.x, t = threadIdx.x;
  if (t < D_EMB) embn[t] = emb[n * D_EMB + t];

  {
    const int o = t >> 2, sub = t & 3;
    const unsigned short* srcW = W_all + (size_t)n * 12288 + o * 192 + sub * 48;
    unsigned short* dstW = Wt + o * EST + sub * 48;
#pragma unroll
    for (int c = 0; c < 6; ++c)
      *(u16x8*)(dstW + c * 8) = *(const u16x8*)(srcW + c * 8);
  }
  for (int idx = t; idx < 1024; idx += 256) {
    int b = idx >> 4, c4 = (idx & 15) * 4;
    f32x4 v = *(const f32x4*)(x + (size_t)(b * N_NODES + n) * 64 + c4);
    u16x4 s;
#pragma unroll
    for (int j = 0; j < 4; ++j) s[j] = f2bf(v[j]);
    *(u16x4*)(xg + b * EST + c4) = s;
  }
  for (int idx = t; idx < 512; idx += 256) {
    int b = idx >> 3, c8 = (idx & 7) * 8;
    *(u16x8*)(xg + b * EST + 64 + c8) = *(const u16x8*)(Y1 + (size_t)n * LD + b * 64 + c8);
  }
  __syncthreads();
  for (int idx = t; idx < 512; idx += 256) {
    int b = idx >> 3, c8 = (idx & 7) * 8;
    u16x8 y2 = *(const u16x8*)(Y2 + (size_t)n * LD + b * 64 + c8);
    u16x8 r;
#pragma unroll
    for (int j = 0; j < 8; ++j)
      r[j] = f2bf(2.f * bf2f(y2[j]) - bf2f(xg[b * EST + c8 + j]));
    *(u16x8*)(xg + b * EST + 128 + c8) = r;
  }
  __syncthreads();

  const int wave = t >> 6, lane = t & 63, quad = lane >> 4;
  const unsigned short* Apx = xg + (wave * 16 + (lane & 15)) * EST + quad * 8;
  f32x4 acc[4] = {};
#pragma unroll
  for (int step = 0; step < 6; ++step) {
    int koff = step * 32;
    bf16x8 a = *(const bf16x8*)(Apx + koff);
#pragma unroll
    for (int nt = 0; nt < 4; ++nt) {
      bf16x8 bfr = *(const bf16x8*)(Wt + (nt * 16 + (lane & 15)) * EST + quad * 8 + koff);
      acc[nt] = __builtin_amdgcn_mfma_f32_16x16x32_bf16(a, bfr, acc[nt], 0, 0, 0);
    }
  }
  float bias[4];
#pragma unroll
  for (int nt = 0; nt < 4; ++nt) {
    float a = 0.f;
#pragma unroll
    for (int d = 0; d < D_EMB; ++d) a += embn[d] * bp[d * 64 + nt * 16 + (lane & 15)];
    bias[nt] = a;
  }
#pragma unroll
  for (int nt = 0; nt < 4; ++nt)
#pragma unroll
    for (int rr = 0; rr < 4; ++rr) {
      int b_row = wave * 16 + quad * 4 + rr;
      out[(size_t)(b_row * N_NODES + n) * 64 + nt * 16 + (lane & 15)] = acc[nt][rr] + bias[nt];
    }
}

extern "C" void kernel_launch(void* const* d_in, const int* in_sizes, int n_in,
                              void* d_out, int out_size, void* d_ws, size_t ws_size,
                              hipStream_t stream) {
  const float* x   = (const float*)d_in[0];
  const float* emb = (const float*)d_in[1];
  const float* wp  = (const float*)d_in[2];
  const float* bp  = (const float*)d_in[3];
  float* out = (float*)d_out;

  const size_t S = (size_t)LD * LD;
  unsigned short* Y1    = (unsigned short*)d_ws;      // slot 0 (live at epilogue)
  unsigned short* Y2    = Y1 + S;                     // slot 1 (live at epilogue)
  unsigned short* Xc    = Y1 + 2 * S;                 // slot 2
  unsigned short* Am    = Y1 + 3 * S;                 // slot 3
  unsigned short* Y1t   = Y1 + 4 * S;                 // slot 4
  unsigned short* wpT   = Xc;                         // 123 KB, written after GEMM2
  unsigned short* W_all = Xc + 256 * 1024;            // 98.3 MB, spans slots 2-4 tail

  transpose_x_kernel<<<dim3(64, 64), 256, 0, stream>>>(x, Xc);
  build_adj_kernel<<<LD, 256, 0, stream>>>(emb, Am);
  gemm256_kernel<true ><<<dim3(16, 16), 512, 0, stream>>>(Am, Xc, Y1, Y1t);
  gemm256_kernel<false><<<dim3(16, 16), 512, 0, stream>>>(Am, Y1t, Y2, nullptr);
  wpt_kernel<<<30, 256, 0, stream>>>(wp, wpT);
  wgen_kernel<<<dim3(48, 80), 256, 0, stream>>>(emb, wpT, W_all);
  epilogue_kernel<<<N_NODES, 256, 0, stream>>>(x, emb, W_all, bp, Y1, Y2, out);
}

// Round 5
// 473.322 us; speedup vs baseline: 1.0276x; 1.0150x over previous
//
#include <hip/hip_runtime.h>

typedef __attribute__((ext_vector_type(8))) __bf16 bf16x8;
typedef __attribute__((ext_vector_type(4))) float f32x4;
typedef __attribute__((ext_vector_type(8))) unsigned short u16x8;
typedef __attribute__((ext_vector_type(4))) unsigned short u16x4;

#define N_NODES 4000
#define LD 4096
#define D_EMB 10
#define NT 64  // K-tiles of 64 over zero-padded K=4096

__device__ __forceinline__ unsigned short f2bf(float f) {
  union { float f; unsigned int u; } v; v.f = f;
  unsigned int r = v.u + 0x7fffu + ((v.u >> 16) & 1u);
  return (unsigned short)(r >> 16);
}
__device__ __forceinline__ float bf2f(unsigned short s) {
  union { unsigned int u; float f; } v; v.u = ((unsigned int)s) << 16;
  return v.f;
}

#define AS1 __attribute__((address_space(1)))
#define AS3 __attribute__((address_space(3)))
__device__ __forceinline__ void gll16(const void* g, void* l) {
  __builtin_amdgcn_global_load_lds((const AS1 void*)g, (AS3 void*)l, 16, 0, 0);
}

// ---------- x [B,M,C] fp32 -> Xc [bc=b*64+c][m] bf16 (row stride 4096) ----------
__global__ __launch_bounds__(256) void transpose_x_kernel(const float* __restrict__ x,
                                                          unsigned short* __restrict__ Xc) {
  __shared__ float tl[64 * 65];
  const int t = threadIdx.x;
  const int m0 = blockIdx.x * 64;
  const int b = blockIdx.y;
#pragma unroll
  for (int rep = 0; rep < 16; ++rep) {
    int idx = rep * 256 + t;
    int ml = idx >> 6, c = idx & 63;
    int m = m0 + ml;
    tl[ml * 65 + c] = (m < N_NODES) ? x[(b * N_NODES + m) * 64 + c] : 0.f;
  }
  __syncthreads();
  const int c_out = t >> 2, q = t & 3;
  u16x8 v0, v1;
#pragma unroll
  for (int j = 0; j < 8; ++j) v0[j] = f2bf(tl[(q * 16 + j) * 65 + c_out]);
#pragma unroll
  for (int j = 0; j < 8; ++j) v1[j] = f2bf(tl[(q * 16 + 8 + j) * 65 + c_out]);
  unsigned short* dst = Xc + (size_t)(b * 64 + c_out) * LD + m0 + q * 16;
  *(u16x8*)dst = v0;
  *(u16x8*)(dst + 8) = v1;
}

// ---------- A = softmax(relu(emb @ emb^T)) rows, bf16; rows/cols 4000..4095 zeroed ----------
__global__ __launch_bounds__(256) void build_adj_kernel(const float* __restrict__ emb,
                                                        unsigned short* __restrict__ A) {
  __shared__ float e_lds[N_NODES];
  __shared__ float embn[16];
  __shared__ float red[16];
  const int n = blockIdx.x, t = threadIdx.x;
  if (n >= N_NODES) {
    for (int m = t; m < LD; m += 256) A[(size_t)n * LD + m] = 0;
    return;
  }
  if (t < D_EMB) embn[t] = emb[n * D_EMB + t];
  __syncthreads();
  float lsum = 0.f;
  for (int m = t; m < N_NODES; m += 256) {
    float dot = 0.f;
#pragma unroll
    for (int d = 0; d < D_EMB; ++d) dot += embn[d] * emb[m * D_EMB + d];
    float e = __expf(fmaxf(dot, 0.f));
    e_lds[m] = e;
    lsum += e;
  }
#pragma unroll
  for (int off = 32; off > 0; off >>= 1) lsum += __shfl_down(lsum, off, 64);
  const int lane = t & 63, wave = t >> 6;
  if (lane == 0) red[wave] = lsum;
  __syncthreads();
  if (t == 0) red[8] = 1.f / (red[0] + red[1] + red[2] + red[3]);
  __syncthreads();
  const float inv = red[8];
  for (int m = t; m < LD; m += 256) {
    float v = (m < N_NODES) ? e_lds[m] * inv : 0.f;
    A[(size_t)n * LD + m] = f2bf(v);
  }
}

// ---------- wp [10][3][64 i][64 o] fp32 -> wpT [10][o*192 + k*64 + i] bf16 ----------
__global__ __launch_bounds__(256) void wpt_kernel(const float* __restrict__ wp,
                                                  unsigned short* __restrict__ wpT) {
  __shared__ float tl[64 * 65];
  const int dk = blockIdx.x;  // 30 blocks: d*3+k
  const int d = dk / 3, k = dk % 3;
  const float* src = wp + (size_t)dk * 4096;
  const int t = threadIdx.x;
#pragma unroll
  for (int rep = 0; rep < 16; ++rep) {
    int idx = rep * 256 + t;
    tl[(idx >> 6) * 65 + (idx & 63)] = src[idx];
  }
  __syncthreads();
#pragma unroll
  for (int rep = 0; rep < 16; ++rep) {
    int idx = rep * 256 + t;
    int o = idx >> 6, i = idx & 63;
    wpT[(size_t)d * 12288 + o * 192 + k * 64 + i] = f2bf(tl[i * 65 + o]);
  }
}

// ---------- W_all[n][j] = sum_d emb[n,d] * wpT[d][j]  (j = o*192+ki), bf16 ----------
__global__ __launch_bounds__(256) void wgen_kernel(const float* __restrict__ emb,
                                                   const unsigned short* __restrict__ wpT,
                                                   unsigned short* __restrict__ W_all) {
  __shared__ float el[50 * D_EMB];
  const int t = threadIdx.x;
  const int j = blockIdx.x * 256 + t;
  const int n0 = blockIdx.y * 50;
  for (int idx = t; idx < 50 * D_EMB; idx += 256) el[idx] = emb[n0 * D_EMB + idx];
  __syncthreads();
  float w[D_EMB];
#pragma unroll
  for (int d = 0; d < D_EMB; ++d) w[d] = bf2f(wpT[(size_t)d * 12288 + j]);
  for (int n = 0; n < 50; ++n) {
    float a = 0.f;
#pragma unroll
    for (int d = 0; d < D_EMB; ++d) a += el[n * D_EMB + d] * w[d];
    W_all[(size_t)(n0 + n) * 12288 + j] = f2bf(a);
  }
}

// ---------- C = A @ B^T, 256x256 tile, BK=64, pipelined quadrant 8-phase (race-fixed) ----------
// Diagnosis (R3): per-phase read->lgkm0->MFMA serializes LDS pipe (~2276cyc/tile CU-wide)
// with MFMA pipe (~2483cyc/tile) -> 4930cyc/tile. Overlap them under the BARRIER DISCIPLINE
// (R4's failure: vmcnt is PER-WAVE; regions are staged by ALL waves; a VM->READ inside a
// phase only covers the reading wave's own loads. Cross-wave safety requires VM at phase
// END, then BAR, then read at next phase START).
// Phase shape: {READ next frags | STAGE | SB0 | MFMA current | LGKM0 [VM8] BAR}.
// MFMA operands were read a phase earlier (drained by that phase-end LGKM0); this phase's
// reads drain under the MFMA cluster. Single-buffered reg sets stay WAR-safe because each
// read lands strictly after its set's last consumer:
//   reads:  P1->b1(T), P2->a1(T), P3->a0(T+1), P4->b0(T+1)   (last uses: P4- ,P4, P2, P3)
//   mfma:   P1:a0*b0  P2:a0*b1  P3:a1*b0  P4:a1*b1
//   stage:  P1:B-H0(P,T+2) P2:A-H0(P,T+2) P3:A-H1(P,T+2) P4:B-H1(P,T+2)
// Stage-over-region safety: each region's last reader drained >=1 barrier earlier
// (B-H0(P): P4(T-1); A-H0(P): P3(T-1); A-H1(P): P2(T); B-H1(P): P1(T)).
// vmcnt ledger (2 loads/stage, FIFO, VM at phase ends only): VM8 at P2-end and P4-end.
//   P1 reads S4(T-2): 8 newer at P4(T-1)-end -> VM8 exact. P2 reads S3(T-2): 10 newer ✓.
//   P3 reads S2(T-1): 8 newer at P2(T)-end -> VM8 exact. P4 reads S1(T-1): 10 newer ✓.
// Prologue: 16 loads (tiles 0,1 in region order), VM8 (forces #1-8: both H of buf0 A,B),
// BAR, read a0(0)/b0(0), LGKM0, BAR.
template <bool WRITE_T>
__global__ __launch_bounds__(512, 2) void gemm256_kernel(const unsigned short* __restrict__ Amat,
                                                         const unsigned short* __restrict__ Bmat,
                                                         unsigned short* __restrict__ Cn,
                                                         unsigned short* __restrict__ Ct) {
  __shared__ __align__(128) char smem[131072];
  const int tid = threadIdx.x;
  const int wave = tid >> 6, lane = tid & 63;
  const int wr = wave >> 2, wc = wave & 3;
  const int bm = blockIdx.y * 256, bn = blockIdx.x * 256;
  const int l15 = lane & 15, quad = lane >> 4;
  const int swz = (lane & 7) << 4;           // row&7 == lane&7 for all frag reads
  const int k0 = (quad * 16) ^ swz;          // ks=0 swizzled col-byte
  const int k1 = (64 + quad * 16) ^ swz;     // ks=1

  const char* Ard = smem + (wr * 128 + l15) * 128;          // + P*32768 + mt*2048 + k0/k1
  const char* Brd = smem + 65536 + (wc * 64 + l15) * 128;   // + P*32768 + nt*2048 + k0/k1

  // staging: per-thread pre-swizzled global bases
  const int u = tid >> 3;
  const int xc = ((tid & 7) ^ (u & 7)) << 3;  // element offset, inverse of read swizzle
  const unsigned short* gA = Amat + (size_t)(bm + u) * LD + xc;
  const unsigned short* gB = Bmat + (size_t)(bn + (u >> 5) * 64 + (u & 31)) * LD + xc;
  // staging LDS dest (wave-uniform; HW adds lane*16)
  char* dA = smem + wave * 1024;
  char* dB = smem + 65536 + (wave >> 2) * 8192 + (wave & 3) * 1024;

#define STAGE_A(P, H, KT) do { \
    gll16(gA + (size_t)((H) * 64) * LD + (KT) * 64,       dA + (P) * 32768 + (H) * 8192); \
    gll16(gA + (size_t)((H) * 64 + 128) * LD + (KT) * 64, dA + (P) * 32768 + (H) * 8192 + 16384); \
  } while (0)
#define STAGE_B(P, H, KT) do { \
    gll16(gB + (size_t)((H) * 32) * LD + (KT) * 64,       dB + (P) * 32768 + (H) * 4096); \
    gll16(gB + (size_t)((H) * 32 + 128) * LD + (KT) * 64, dB + (P) * 32768 + (H) * 4096 + 16384); \
  } while (0)
#define BAR __builtin_amdgcn_s_barrier()
#define LGKM0 asm volatile("s_waitcnt lgkmcnt(0)" ::: "memory")
#define VM8  asm volatile("s_waitcnt vmcnt(8)" ::: "memory")
#define SB0 __builtin_amdgcn_sched_barrier(0)
#define SETP1 __builtin_amdgcn_s_setprio(1)
#define SETP0 __builtin_amdgcn_s_setprio(0)

  f32x4 acc[8][4] = {};
  bf16x8 a0[4][2], a1[4][2], b0[2][2], b1[2][2];

#define READ_A(DST, MH, P) do { _Pragma("unroll") for (int m = 0; m < 4; ++m) { \
    DST[m][0] = *(const bf16x8*)(Ard + (P) * 32768 + ((MH) * 4 + m) * 2048 + k0); \
    DST[m][1] = *(const bf16x8*)(Ard + (P) * 32768 + ((MH) * 4 + m) * 2048 + k1); } } while (0)
#define READ_B(DST, NH, P) do { _Pragma("unroll") for (int n = 0; n < 2; ++n) { \
    DST[n][0] = *(const bf16x8*)(Brd + (P) * 32768 + ((NH) * 2 + n) * 2048 + k0); \
    DST[n][1] = *(const bf16x8*)(Brd + (P) * 32768 + ((NH) * 2 + n) * 2048 + k1); } } while (0)
#define MFMA_Q(AR, BR, MH, NH) do { _Pragma("unroll") for (int m = 0; m < 4; ++m) \
    _Pragma("unroll") for (int n = 0; n < 2; ++n) { \
      f32x4 c = acc[(MH) * 4 + m][(NH) * 2 + n]; \
      c = __builtin_amdgcn_mfma_f32_16x16x32_bf16(AR[m][0], BR[n][0], c, 0, 0, 0); \
      c = __builtin_amdgcn_mfma_f32_16x16x32_bf16(AR[m][1], BR[n][1], c, 0, 0, 0); \
      acc[(MH) * 4 + m][(NH) * 2 + n] = c; } } while (0)

  // prologue: stage tiles 0,1 in steady-state region order (FIFO #1-16)
  STAGE_B(0, 0, 0);   // #1-2   B-H0(0)
  STAGE_A(0, 0, 0);   // #3-4   A-H0(0)
  STAGE_A(0, 1, 0);   // #5-6   A-H1(0)
  STAGE_B(0, 1, 0);   // #7-8   B-H1(0)
  STAGE_B(1, 0, 1);   // #9-10  B-H0(1)
  STAGE_A(1, 0, 1);   // #11-12 A-H0(1)
  STAGE_A(1, 1, 1);   // #13-14 A-H1(1)
  STAGE_B(1, 1, 1);   // #15-16 B-H1(1)
  VM8;                // forces #1-8 complete (A/B both halves of tile 0)
  BAR;                // cross-wave: all waves' tile-0 loads landed
  READ_A(a0, 0, 0);
  READ_B(b0, 0, 0);
  LGKM0;              // a0/b0 in regs before P1(0) stages over B-H0(0)
  BAR;

#define TILE(T, P, Q) do { \
    const int kt2 = ((T) + 2 < NT) ? (T) + 2 : 0; /* clamped: dead loads, live vmcnt count */ \
    /* P1: read b1(T); stage B-H0(P,T+2); mfma a0*b0 */ \
    READ_B(b1, 1, P); \
    STAGE_B(P, 0, kt2); \
    SB0; \
    SETP1; MFMA_Q(a0, b0, 0, 0); SETP0; \
    LGKM0; BAR; \
    /* P2: read a1(T); stage A-H0(P,T+2); mfma a0*b1 */ \
    READ_A(a1, 1, P); \
    STAGE_A(P, 0, kt2); \
    SB0; \
    SETP1; MFMA_Q(a0, b1, 0, 1); SETP0; \
    LGKM0; VM8; BAR; \
    /* P3: read a0(T+1); stage A-H1(P,T+2); mfma a1*b0 */ \
    READ_A(a0, 0, Q); \
    STAGE_A(P, 1, kt2); \
    SB0; \
    SETP1; MFMA_Q(a1, b0, 1, 0); SETP0; \
    LGKM0; BAR; \
    /* P4: read b0(T+1); stage B-H1(P,T+2); mfma a1*b1 */ \
    READ_B(b0, 0, Q); \
    STAGE_B(P, 1, kt2); \
    SB0; \
    SETP1; MFMA_Q(a1, b1, 1, 1); SETP0; \
    LGKM0; VM8; BAR; \
  } while (0)

#pragma unroll 1
  for (int t = 0; t < NT; t += 2) {
    TILE(t, 0, 1);
    TILE(t + 1, 1, 0);
  }

  // direct C write (registers only)
#pragma unroll
  for (int mt = 0; mt < 8; ++mt)
#pragma unroll
    for (int nt = 0; nt < 4; ++nt) {
      const int row0 = bm + wr * 128 + mt * 16 + quad * 4;
      const int col = bn + wc * 64 + nt * 16 + l15;
#pragma unroll
      for (int r = 0; r < 4; ++r)
        Cn[(size_t)(row0 + r) * LD + col] = f2bf(acc[mt][nt][r]);
    }

  if (WRITE_T) {
    unsigned short* tr = (unsigned short*)smem;  // [128 cols][264] per chunk
    asm volatile("s_waitcnt vmcnt(0)" ::: "memory");  // drain dead prefetches before smem reuse
    __syncthreads();
#pragma unroll
    for (int ch = 0; ch < 2; ++ch) {
      if ((wc >> 1) == ch) {
#pragma unroll
        for (int mt = 0; mt < 8; ++mt)
#pragma unroll
          for (int nt = 0; nt < 4; ++nt) {
            const int coll = (wc & 1) * 64 + nt * 16 + l15;
            const int row0 = wr * 128 + mt * 16 + quad * 4;
#pragma unroll
            for (int r = 0; r < 4; ++r)
              tr[coll * 264 + row0 + r] = f2bf(acc[mt][nt][r]);
          }
      }
      __syncthreads();
      {
        const int coll = tid >> 2, seg = tid & 3;
        const unsigned short* src = tr + coll * 264 + seg * 64;
        unsigned short* dst = Ct + (size_t)(bn + ch * 128 + coll) * LD + bm + seg * 64;
#pragma unroll
        for (int j = 0; j < 8; ++j)
          *(u16x8*)(dst + j * 8) = *(const u16x8*)(src + j * 8);
      }
      __syncthreads();
    }
  } else {
    asm volatile("s_waitcnt vmcnt(0)" ::: "memory");  // drain dead prefetches before endpgm
  }
#undef TILE
#undef MFMA_Q
#undef READ_B
#undef READ_A
#undef SETP0
#undef SETP1
#undef SB0
#undef VM8
#undef LGKM0
#undef BAR
#undef STAGE_B
#undef STAGE_A
}

// ---------- fused per-node epilogue via MFMA; W streamed from precomputed W_all ----------
#define EST 200  // LDS row stride (elements): 400 B, 16-B aligned
__global__ __launch_bounds__(256) void epilogue_kernel(const float* __restrict__ x,
                                                       const float* __restrict__ emb,
                                                       const unsigned short* __restrict__ W_all,
                                                       const float* __restrict__ bp,
                                                       const unsigned short* __restrict__ Y1,
                                                       const unsigned short* __restrict__ Y2,
                                                       float* __restrict__ out) {
  __shared__ unsigned short Wt[64 * EST];  // [o][ki]
  __shared__ unsigned short xg[64 * EST];  // [b][ki]
  __shared__ float embn[16];
  const int n = blockIdx.x, t = threadIdx.x;
  if (t < D_EMB) embn[t] = emb[n * D_EMB + t];

  {
    const int o = t >> 2, sub = t & 3;
    const unsigned short* srcW = W_all + (size_t)n * 12288 + o * 192 + sub * 48;
    unsigned short* dstW = Wt + o * EST + sub * 48;
#pragma unroll
    for (int c = 0; c < 6; ++c)
      *(u16x8*)(dstW + c * 8) = *(const u16x8*)(srcW + c * 8);
  }
  for (int idx = t; idx < 1024; idx += 256) {
    int b = idx >> 4, c4 = (idx & 15) * 4;
    f32x4 v = *(const f32x4*)(x + (size_t)(b * N_NODES + n) * 64 + c4);
    u16x4 s;
#pragma unroll
    for (int j = 0; j < 4; ++j) s[j] = f2bf(v[j]);
    *(u16x4*)(xg + b * EST + c4) = s;
  }
  for (int idx = t; idx < 512; idx += 256) {
    int b = idx >> 3, c8 = (idx & 7) * 8;
    *(u16x8*)(xg + b * EST + 64 + c8) = *(const u16x8*)(Y1 + (size_t)n * LD + b * 64 + c8);
  }
  __syncthreads();
  for (int idx = t; idx < 512; idx += 256) {
    int b = idx >> 3, c8 = (idx & 7) * 8;
    u16x8 y2 = *(const u16x8*)(Y2 + (size_t)n * LD + b * 64 + c8);
    u16x8 r;
#pragma unroll
    for (int j = 0; j < 8; ++j)
      r[j] = f2bf(2.f * bf2f(y2[j]) - bf2f(xg[b * EST + c8 + j]));
    *(u16x8*)(xg + b * EST + 128 + c8) = r;
  }
  __syncthreads();

  const int wave = t >> 6, lane = t & 63, quad = lane >> 4;
  const unsigned short* Apx = xg + (wave * 16 + (lane & 15)) * EST + quad * 8;
  f32x4 acc[4] = {};
#pragma unroll
  for (int step = 0; step < 6; ++step) {
    int koff = step * 32;
    bf16x8 a = *(const bf16x8*)(Apx + koff);
#pragma unroll
    for (int nt = 0; nt < 4; ++nt) {
      bf16x8 bfr = *(const bf16x8*)(Wt + (nt * 16 + (lane & 15)) * EST + quad * 8 + koff);
      acc[nt] = __builtin_amdgcn_mfma_f32_16x16x32_bf16(a, bfr, acc[nt], 0, 0, 0);
    }
  }
  float bias[4];
#pragma unroll
  for (int nt = 0; nt < 4; ++nt) {
    float a = 0.f;
#pragma unroll
    for (int d = 0; d < D_EMB; ++d) a += embn[d] * bp[d * 64 + nt * 16 + (lane & 15)];
    bias[nt] = a;
  }
#pragma unroll
  for (int nt = 0; nt < 4; ++nt)
#pragma unroll
    for (int rr = 0; rr < 4; ++rr) {
      int b_row = wave * 16 + quad * 4 + rr;
      out[(size_t)(b_row * N_NODES + n) * 64 + nt * 16 + (lane & 15)] = acc[nt][rr] + bias[nt];
    }
}

extern "C" void kernel_launch(void* const* d_in, const int* in_sizes, int n_in,
                              void* d_out, int out_size, void* d_ws, size_t ws_size,
                              hipStream_t stream) {
  const float* x   = (const float*)d_in[0];
  const float* emb = (const float*)d_in[1];
  const float* wp  = (const float*)d_in[2];
  const float* bp  = (const float*)d_in[3];
  float* out = (float*)d_out;

  const size_t S = (size_t)LD * LD;
  unsigned short* Y1    = (unsigned short*)d_ws;      // slot 0 (live at epilogue)
  unsigned short* Y2    = Y1 + S;                     // slot 1 (live at epilogue)
  unsigned short* Xc    = Y1 + 2 * S;                 // slot 2
  unsigned short* Am    = Y1 + 3 * S;                 // slot 3
  unsigned short* Y1t   = Y1 + 4 * S;                 // slot 4
  unsigned short* wpT   = Xc;                         // 123 KB, written after GEMM2
  unsigned short* W_all = Xc + 256 * 1024;            // 98.3 MB, spans slots 2-4 tail

  transpose_x_kernel<<<dim3(64, 64), 256, 0, stream>>>(x, Xc);
  build_adj_kernel<<<LD, 256, 0, stream>>>(emb, Am);
  gemm256_kernel<true ><<<dim3(16, 16), 512, 0, stream>>>(Am, Xc, Y1, Y1t);
  gemm256_kernel<false><<<dim3(16, 16), 512, 0, stream>>>(Am, Y1t, Y2, nullptr);
  wpt_kernel<<<30, 256, 0, stream>>>(wp, wpT);
  wgen_kernel<<<dim3(48, 80), 256, 0, stream>>>(emb, wpT, W_all);
  epilogue_kernel<<<N_NODES, 256, 0, stream>>>(x, emb, W_all, bp, Y1, Y2, out);
}